// Round 1
// baseline (743.230 us; speedup 1.0000x reference)
//
#include <hip/hip_runtime.h>
#include <cmath>

constexpr unsigned HASH_SIZE = 1u << 19;
constexpr unsigned HASH_MASK = HASH_SIZE - 1u;
constexpr unsigned P2 = 2654435761u;
constexpr unsigned P3 = 805459861u;

struct ResArr { float r[16]; };

typedef float f4 __attribute__((ext_vector_type(4)));

__device__ __forceinline__ unsigned flipF(float f) {
    unsigned u = __float_as_uint(f);
    return (u & 0x80000000u) ? ~u : (u | 0x80000000u);
}
__device__ __forceinline__ float unflipF(unsigned u) {
    unsigned b = (u & 0x80000000u) ? (u ^ 0x80000000u) : ~u;
    return __uint_as_float(b);
}

__global__ void he_init_minmax(unsigned* __restrict__ ws) {
    int t = threadIdx.x;
    if (t < 3) ws[t] = 0xFFFFFFFFu;   // min slots (flipped encoding)
    else if (t < 6) ws[t] = 0u;       // max slots
}

__global__ __launch_bounds__(256) void he_minmax(const float* __restrict__ x, int n,
                                                 unsigned* __restrict__ ws) {
    int tid = blockIdx.x * blockDim.x + threadIdx.x;
    int stride = gridDim.x * blockDim.x;
    float mn0 = INFINITY, mn1 = INFINITY, mn2 = INFINITY;
    float mx0 = -INFINITY, mx1 = -INFINITY, mx2 = -INFINITY;
    for (int i = tid; i < n; i += stride) {
        float a = x[3 * i + 0];
        float b = x[3 * i + 1];
        float c = x[3 * i + 2];
        mn0 = fminf(mn0, a); mx0 = fmaxf(mx0, a);
        mn1 = fminf(mn1, b); mx1 = fmaxf(mx1, b);
        mn2 = fminf(mn2, c); mx2 = fmaxf(mx2, c);
    }
    #pragma unroll
    for (int off = 32; off > 0; off >>= 1) {
        mn0 = fminf(mn0, __shfl_down(mn0, off));
        mn1 = fminf(mn1, __shfl_down(mn1, off));
        mn2 = fminf(mn2, __shfl_down(mn2, off));
        mx0 = fmaxf(mx0, __shfl_down(mx0, off));
        mx1 = fmaxf(mx1, __shfl_down(mx1, off));
        mx2 = fmaxf(mx2, __shfl_down(mx2, off));
    }
    if ((threadIdx.x & 63) == 0) {
        atomicMin(&ws[0], flipF(mn0));
        atomicMin(&ws[1], flipF(mn1));
        atomicMin(&ws[2], flipF(mn2));
        atomicMax(&ws[3], flipF(mx0));
        atomicMax(&ws[4], flipF(mx1));
        atomicMax(&ws[5], flipF(mx2));
    }
}

__global__ __launch_bounds__(256) void he_encode(const float* __restrict__ x,
                                                 const float* __restrict__ tables,
                                                 const unsigned* __restrict__ mm,
                                                 float* __restrict__ out, int n, ResArr res) {
    int i = blockIdx.x * 256 + threadIdx.x;
    if (i >= n) return;

    float mn0 = unflipF(mm[0]), mn1 = unflipF(mm[1]), mn2 = unflipF(mm[2]);
    float mx0 = unflipF(mm[3]), mx1 = unflipF(mm[4]), mx2 = unflipF(mm[5]);
    float den0 = (mx0 - mn0) + 1e-8f;
    float den1 = (mx1 - mn1) + 1e-8f;
    float den2 = (mx2 - mn2) + 1e-8f;

    float px = x[3 * i + 0], py = x[3 * i + 1], pz = x[3 * i + 2];
    float xs = (px - mn0) / den0;
    float ys = (py - mn1) / den1;
    float zs = (pz - mn2) / den2;

    float o[32];

    #pragma unroll
    for (int l = 0; l < 16; ++l) {
        float R = res.r[l];
        float xg = xs * R, yg = ys * R, zg = zs * R;
        float fx = floorf(xg), fy = floorf(yg), fz = floorf(zg);
        float tx = xg - fx, ty = yg - fy, tz = zg - fz;
        unsigned cx = (unsigned)fx, cy = (unsigned)fy, cz = (unsigned)fz;

        unsigned hx0 = cx,            hx1 = cx + 1u;
        unsigned hy0 = cy * P2,       hy1 = hy0 + P2;
        unsigned hz0 = cz * P3,       hz1 = hz0 + P3;

        const float2* __restrict__ T = (const float2*)tables + (size_t)l * HASH_SIZE;

        unsigned i000 = (hx0 ^ hy0 ^ hz0) & HASH_MASK;
        unsigned i100 = (hx1 ^ hy0 ^ hz0) & HASH_MASK;
        unsigned i010 = (hx0 ^ hy1 ^ hz0) & HASH_MASK;
        unsigned i110 = (hx1 ^ hy1 ^ hz0) & HASH_MASK;
        unsigned i001 = (hx0 ^ hy0 ^ hz1) & HASH_MASK;
        unsigned i101 = (hx1 ^ hy0 ^ hz1) & HASH_MASK;
        unsigned i011 = (hx0 ^ hy1 ^ hz1) & HASH_MASK;
        unsigned i111 = (hx1 ^ hy1 ^ hz1) & HASH_MASK;

        float2 f000 = T[i000];
        float2 f100 = T[i100];
        float2 f010 = T[i010];
        float2 f110 = T[i110];
        float2 f001 = T[i001];
        float2 f101 = T[i101];
        float2 f011 = T[i011];
        float2 f111 = T[i111];

        float wx0 = 1.0f - tx, wx1 = tx;
        float wy0 = 1.0f - ty, wy1 = ty;
        float wz0 = 1.0f - tz, wz1 = tz;

        float w000 = wx0 * wy0 * wz0;
        float w100 = wx1 * wy0 * wz0;
        float w010 = wx0 * wy1 * wz0;
        float w110 = wx1 * wy1 * wz0;
        float w001 = wx0 * wy0 * wz1;
        float w101 = wx1 * wy0 * wz1;
        float w011 = wx0 * wy1 * wz1;
        float w111 = wx1 * wy1 * wz1;

        float a0 = w000 * f000.x;
        float a1 = w000 * f000.y;
        a0 += w100 * f100.x;  a1 += w100 * f100.y;
        a0 += w010 * f010.x;  a1 += w010 * f010.y;
        a0 += w110 * f110.x;  a1 += w110 * f110.y;
        a0 += w001 * f001.x;  a1 += w001 * f001.y;
        a0 += w101 * f101.x;  a1 += w101 * f101.y;
        a0 += w011 * f011.x;  a1 += w011 * f011.y;
        a0 += w111 * f111.x;  a1 += w111 * f111.y;

        o[2 * l + 0] = a0;
        o[2 * l + 1] = a1;
    }

    float* op = out + (size_t)i * 32;
    #pragma unroll
    for (int k = 0; k < 8; ++k) {
        f4 v;
        v.x = o[4 * k + 0];
        v.y = o[4 * k + 1];
        v.z = o[4 * k + 2];
        v.w = o[4 * k + 3];
        __builtin_nontemporal_store(v, (f4*)(op + 4 * k));
    }
}

extern "C" void kernel_launch(void* const* d_in, const int* in_sizes, int n_in,
                              void* d_out, int out_size, void* d_ws, size_t ws_size,
                              hipStream_t stream) {
    const float* x = (const float*)d_in[0];
    const float* tables = (const float*)d_in[1];
    float* out = (float*)d_out;
    unsigned* ws = (unsigned*)d_ws;
    int n = in_sizes[0] / 3;

    // Replicate the reference's host-side resolution computation (numpy float64
    // scalar ufuncs defer to libm; int() truncates toward zero, as does the cast).
    ResArr res;
    double growth = exp((log(512.0) - log(16.0)) / 15.0);
    for (int l = 0; l < 16; ++l) {
        res.r[l] = (float)(int)(16.0 * pow(growth, (double)l));
    }

    he_init_minmax<<<1, 64, 0, stream>>>(ws);
    he_minmax<<<1024, 256, 0, stream>>>(x, n, ws);
    int blocks = (n + 255) / 256;
    he_encode<<<blocks, 256, 0, stream>>>(x, tables, ws, out, n, res);
}

// Round 2
// 481.335 us; speedup vs baseline: 1.5441x; 1.5441x over previous
//
#include <hip/hip_runtime.h>
#include <cmath>

constexpr unsigned HASH_SIZE = 1u << 19;
constexpr unsigned HASH_MASK = HASH_SIZE - 1u;
constexpr unsigned P2 = 2654435761u;
constexpr unsigned P3 = 805459861u;

struct ResArr { float r[16]; };

typedef float f4 __attribute__((ext_vector_type(4)));

// ---------------- stage 1: per-block min/max partials (no atomics) ----------
__global__ __launch_bounds__(256) void he_minmax1(const float* __restrict__ x, int n,
                                                  float* __restrict__ part) {
    int tid = blockIdx.x * blockDim.x + threadIdx.x;
    int stride = gridDim.x * blockDim.x;
    float mn0 = INFINITY, mn1 = INFINITY, mn2 = INFINITY;
    float mx0 = -INFINITY, mx1 = -INFINITY, mx2 = -INFINITY;
    for (int i = tid; i < n; i += stride) {
        float a = x[3 * i + 0];
        float b = x[3 * i + 1];
        float c = x[3 * i + 2];
        mn0 = fminf(mn0, a); mx0 = fmaxf(mx0, a);
        mn1 = fminf(mn1, b); mx1 = fmaxf(mx1, b);
        mn2 = fminf(mn2, c); mx2 = fmaxf(mx2, c);
    }
    #pragma unroll
    for (int off = 32; off > 0; off >>= 1) {
        mn0 = fminf(mn0, __shfl_down(mn0, off));
        mn1 = fminf(mn1, __shfl_down(mn1, off));
        mn2 = fminf(mn2, __shfl_down(mn2, off));
        mx0 = fmaxf(mx0, __shfl_down(mx0, off));
        mx1 = fmaxf(mx1, __shfl_down(mx1, off));
        mx2 = fmaxf(mx2, __shfl_down(mx2, off));
    }
    __shared__ float s[6][4];
    int w = threadIdx.x >> 6;
    if ((threadIdx.x & 63) == 0) {
        s[0][w] = mn0; s[1][w] = mn1; s[2][w] = mn2;
        s[3][w] = mx0; s[4][w] = mx1; s[5][w] = mx2;
    }
    __syncthreads();
    if (threadIdx.x == 0) {
        float* p = part + 6 * blockIdx.x;
        p[0] = fminf(fminf(s[0][0], s[0][1]), fminf(s[0][2], s[0][3]));
        p[1] = fminf(fminf(s[1][0], s[1][1]), fminf(s[1][2], s[1][3]));
        p[2] = fminf(fminf(s[2][0], s[2][1]), fminf(s[2][2], s[2][3]));
        p[3] = fmaxf(fmaxf(s[3][0], s[3][1]), fmaxf(s[3][2], s[3][3]));
        p[4] = fmaxf(fmaxf(s[4][0], s[4][1]), fmaxf(s[4][2], s[4][3]));
        p[5] = fmaxf(fmaxf(s[5][0], s[5][1]), fmaxf(s[5][2], s[5][3]));
    }
}

// ---------------- stage 2: combine 256 partials (single block) --------------
__global__ __launch_bounds__(256) void he_minmax2(const float* __restrict__ part,
                                                  float* __restrict__ mm) {
    int t = threadIdx.x;  // 256 threads, one partial each
    const float* p = part + 6 * t;
    float mn0 = p[0], mn1 = p[1], mn2 = p[2];
    float mx0 = p[3], mx1 = p[4], mx2 = p[5];
    #pragma unroll
    for (int off = 32; off > 0; off >>= 1) {
        mn0 = fminf(mn0, __shfl_down(mn0, off));
        mn1 = fminf(mn1, __shfl_down(mn1, off));
        mn2 = fminf(mn2, __shfl_down(mn2, off));
        mx0 = fmaxf(mx0, __shfl_down(mx0, off));
        mx1 = fmaxf(mx1, __shfl_down(mx1, off));
        mx2 = fmaxf(mx2, __shfl_down(mx2, off));
    }
    __shared__ float s[6][4];
    int w = t >> 6;
    if ((t & 63) == 0) {
        s[0][w] = mn0; s[1][w] = mn1; s[2][w] = mn2;
        s[3][w] = mx0; s[4][w] = mx1; s[5][w] = mx2;
    }
    __syncthreads();
    if (t == 0) {
        mm[0] = fminf(fminf(s[0][0], s[0][1]), fminf(s[0][2], s[0][3]));
        mm[1] = fminf(fminf(s[1][0], s[1][1]), fminf(s[1][2], s[1][3]));
        mm[2] = fminf(fminf(s[2][0], s[2][1]), fminf(s[2][2], s[2][3]));
        mm[3] = fmaxf(fmaxf(s[3][0], s[3][1]), fmaxf(s[3][2], s[3][3]));
        mm[4] = fmaxf(fmaxf(s[4][0], s[4][1]), fmaxf(s[4][2], s[4][3]));
        mm[5] = fmaxf(fmaxf(s[5][0], s[5][1]), fmaxf(s[5][2], s[5][3]));
    }
}

// ---------------- encode: 2 levels interleaved for 16 loads in flight -------
__global__ __launch_bounds__(256) void he_encode(const float* __restrict__ x,
                                                 const float* __restrict__ tables,
                                                 const float* __restrict__ mm,
                                                 float* __restrict__ out, int n, ResArr res) {
    int i = blockIdx.x * 256 + threadIdx.x;
    if (i >= n) return;

    float den0 = (mm[3] - mm[0]) + 1e-8f;
    float den1 = (mm[4] - mm[1]) + 1e-8f;
    float den2 = (mm[5] - mm[2]) + 1e-8f;

    float px = x[3 * i + 0], py = x[3 * i + 1], pz = x[3 * i + 2];
    float xs = (px - mm[0]) / den0;
    float ys = (py - mm[1]) / den1;
    float zs = (pz - mm[2]) / den2;

    float* op = out + (size_t)i * 32;

    #pragma unroll
    for (int lp = 0; lp < 8; ++lp) {
        float2 f[2][8];
        float tx[2], ty[2], tz[2];

        #pragma unroll
        for (int s = 0; s < 2; ++s) {
            int l = 2 * lp + s;
            float R = res.r[l];
            float xg = xs * R, yg = ys * R, zg = zs * R;
            float fx = floorf(xg), fy = floorf(yg), fz = floorf(zg);
            tx[s] = xg - fx; ty[s] = yg - fy; tz[s] = zg - fz;
            unsigned cx = (unsigned)fx, cy = (unsigned)fy, cz = (unsigned)fz;

            unsigned hx0 = cx,      hx1 = cx + 1u;
            unsigned hy0 = cy * P2, hy1 = hy0 + P2;
            unsigned hz0 = cz * P3, hz1 = hz0 + P3;

            const float2* __restrict__ T = (const float2*)tables + (size_t)l * HASH_SIZE;

            f[s][0] = T[(hx0 ^ hy0 ^ hz0) & HASH_MASK];
            f[s][1] = T[(hx1 ^ hy0 ^ hz0) & HASH_MASK];
            f[s][2] = T[(hx0 ^ hy1 ^ hz0) & HASH_MASK];
            f[s][3] = T[(hx1 ^ hy1 ^ hz0) & HASH_MASK];
            f[s][4] = T[(hx0 ^ hy0 ^ hz1) & HASH_MASK];
            f[s][5] = T[(hx1 ^ hy0 ^ hz1) & HASH_MASK];
            f[s][6] = T[(hx0 ^ hy1 ^ hz1) & HASH_MASK];
            f[s][7] = T[(hx1 ^ hy1 ^ hz1) & HASH_MASK];
        }

        f4 v;
        #pragma unroll
        for (int s = 0; s < 2; ++s) {
            float wx0 = 1.0f - tx[s], wx1 = tx[s];
            float wy0 = 1.0f - ty[s], wy1 = ty[s];
            float wz0 = 1.0f - tz[s], wz1 = tz[s];

            float w0 = wx0 * wy0 * wz0;
            float w1 = wx1 * wy0 * wz0;
            float w2 = wx0 * wy1 * wz0;
            float w3 = wx1 * wy1 * wz0;
            float w4 = wx0 * wy0 * wz1;
            float w5 = wx1 * wy0 * wz1;
            float w6 = wx0 * wy1 * wz1;
            float w7 = wx1 * wy1 * wz1;

            float a0 = w0 * f[s][0].x;
            float a1 = w0 * f[s][0].y;
            a0 += w1 * f[s][1].x;  a1 += w1 * f[s][1].y;
            a0 += w2 * f[s][2].x;  a1 += w2 * f[s][2].y;
            a0 += w3 * f[s][3].x;  a1 += w3 * f[s][3].y;
            a0 += w4 * f[s][4].x;  a1 += w4 * f[s][4].y;
            a0 += w5 * f[s][5].x;  a1 += w5 * f[s][5].y;
            a0 += w6 * f[s][6].x;  a1 += w6 * f[s][6].y;
            a0 += w7 * f[s][7].x;  a1 += w7 * f[s][7].y;

            if (s == 0) { v.x = a0; v.y = a1; }
            else        { v.z = a0; v.w = a1; }
        }
        *(f4*)(op + 4 * lp) = v;   // plain store (nt caused HBM write amplification)
    }
}

extern "C" void kernel_launch(void* const* d_in, const int* in_sizes, int n_in,
                              void* d_out, int out_size, void* d_ws, size_t ws_size,
                              hipStream_t stream) {
    const float* x = (const float*)d_in[0];
    const float* tables = (const float*)d_in[1];
    float* out = (float*)d_out;
    float* part = (float*)d_ws;                 // 256*6 floats
    float* mm = (float*)d_ws + 2048;            // 6 floats, separate region
    int n = in_sizes[0] / 3;

    // Replicate the reference's host-side resolution computation (libm f64).
    ResArr res;
    double growth = exp((log(512.0) - log(16.0)) / 15.0);
    for (int l = 0; l < 16; ++l) {
        res.r[l] = (float)(int)(16.0 * pow(growth, (double)l));
    }

    he_minmax1<<<256, 256, 0, stream>>>(x, n, part);
    he_minmax2<<<1, 256, 0, stream>>>(part, mm);
    int blocks = (n + 255) / 256;
    he_encode<<<blocks, 256, 0, stream>>>(x, tables, mm, out, n, res);
}

// Round 3
// 476.690 us; speedup vs baseline: 1.5591x; 1.0097x over previous
//
#include <hip/hip_runtime.h>
#include <cmath>

constexpr unsigned HASH_SIZE = 1u << 19;
constexpr unsigned HASH_MASK = HASH_SIZE - 1u;
constexpr unsigned P2 = 2654435761u;
constexpr unsigned P3 = 805459861u;

struct ResArr { float r[16]; };

typedef float f4 __attribute__((ext_vector_type(4)));

// ---------------- stage 1: per-block min/max partials (no atomics) ----------
__global__ __launch_bounds__(256) void he_minmax1(const float* __restrict__ x, int n,
                                                  float* __restrict__ part) {
    int tid = blockIdx.x * blockDim.x + threadIdx.x;
    int stride = gridDim.x * blockDim.x;
    float mn0 = INFINITY, mn1 = INFINITY, mn2 = INFINITY;
    float mx0 = -INFINITY, mx1 = -INFINITY, mx2 = -INFINITY;
    for (int i = tid; i < n; i += stride) {
        float a = x[3 * i + 0];
        float b = x[3 * i + 1];
        float c = x[3 * i + 2];
        mn0 = fminf(mn0, a); mx0 = fmaxf(mx0, a);
        mn1 = fminf(mn1, b); mx1 = fmaxf(mx1, b);
        mn2 = fminf(mn2, c); mx2 = fmaxf(mx2, c);
    }
    #pragma unroll
    for (int off = 32; off > 0; off >>= 1) {
        mn0 = fminf(mn0, __shfl_down(mn0, off));
        mn1 = fminf(mn1, __shfl_down(mn1, off));
        mn2 = fminf(mn2, __shfl_down(mn2, off));
        mx0 = fmaxf(mx0, __shfl_down(mx0, off));
        mx1 = fmaxf(mx1, __shfl_down(mx1, off));
        mx2 = fmaxf(mx2, __shfl_down(mx2, off));
    }
    __shared__ float s[6][4];
    int w = threadIdx.x >> 6;
    if ((threadIdx.x & 63) == 0) {
        s[0][w] = mn0; s[1][w] = mn1; s[2][w] = mn2;
        s[3][w] = mx0; s[4][w] = mx1; s[5][w] = mx2;
    }
    __syncthreads();
    if (threadIdx.x == 0) {
        float* p = part + 6 * blockIdx.x;
        p[0] = fminf(fminf(s[0][0], s[0][1]), fminf(s[0][2], s[0][3]));
        p[1] = fminf(fminf(s[1][0], s[1][1]), fminf(s[1][2], s[1][3]));
        p[2] = fminf(fminf(s[2][0], s[2][1]), fminf(s[2][2], s[2][3]));
        p[3] = fmaxf(fmaxf(s[3][0], s[3][1]), fmaxf(s[3][2], s[3][3]));
        p[4] = fmaxf(fmaxf(s[4][0], s[4][1]), fmaxf(s[4][2], s[4][3]));
        p[5] = fmaxf(fmaxf(s[5][0], s[5][1]), fmaxf(s[5][2], s[5][3]));
    }
}

// ---------------- stage 2: combine 256 partials (single block) --------------
__global__ __launch_bounds__(256) void he_minmax2(const float* __restrict__ part,
                                                  float* __restrict__ mm) {
    int t = threadIdx.x;  // 256 threads, one partial each
    const float* p = part + 6 * t;
    float mn0 = p[0], mn1 = p[1], mn2 = p[2];
    float mx0 = p[3], mx1 = p[4], mx2 = p[5];
    #pragma unroll
    for (int off = 32; off > 0; off >>= 1) {
        mn0 = fminf(mn0, __shfl_down(mn0, off));
        mn1 = fminf(mn1, __shfl_down(mn1, off));
        mn2 = fminf(mn2, __shfl_down(mn2, off));
        mx0 = fmaxf(mx0, __shfl_down(mx0, off));
        mx1 = fmaxf(mx1, __shfl_down(mx1, off));
        mx2 = fmaxf(mx2, __shfl_down(mx2, off));
    }
    __shared__ float s[6][4];
    int w = t >> 6;
    if ((t & 63) == 0) {
        s[0][w] = mn0; s[1][w] = mn1; s[2][w] = mn2;
        s[3][w] = mx0; s[4][w] = mx1; s[5][w] = mx2;
    }
    __syncthreads();
    if (t == 0) {
        mm[0] = fminf(fminf(s[0][0], s[0][1]), fminf(s[0][2], s[0][3]));
        mm[1] = fminf(fminf(s[1][0], s[1][1]), fminf(s[1][2], s[1][3]));
        mm[2] = fminf(fminf(s[2][0], s[2][1]), fminf(s[2][2], s[2][3]));
        mm[3] = fmaxf(fmaxf(s[3][0], s[3][1]), fmaxf(s[3][2], s[3][3]));
        mm[4] = fmaxf(fmaxf(s[4][0], s[4][1]), fmaxf(s[4][2], s[4][3]));
        mm[5] = fmaxf(fmaxf(s[5][0], s[5][1]), fmaxf(s[5][2], s[5][3]));
    }
}

// ---------------- encode: XOR-adjacency paired gathers ----------------------
__global__ __launch_bounds__(256) void he_encode(const float* __restrict__ x,
                                                 const float* __restrict__ tables,
                                                 const float* __restrict__ mm,
                                                 float* __restrict__ out, int n, ResArr res) {
    int i = blockIdx.x * 256 + threadIdx.x;
    if (i >= n) return;

    float den0 = (mm[3] - mm[0]) + 1e-8f;
    float den1 = (mm[4] - mm[1]) + 1e-8f;
    float den2 = (mm[5] - mm[2]) + 1e-8f;

    float px = x[3 * i + 0], py = x[3 * i + 1], pz = x[3 * i + 2];
    float xs = (px - mm[0]) / den0;
    float ys = (py - mm[1]) / den1;
    float zs = (pz - mm[2]) / den2;

    float o[32];

    #pragma unroll
    for (int l = 0; l < 16; ++l) {
        float R = res.r[l];
        float xg = xs * R, yg = ys * R, zg = zs * R;
        float fx = floorf(xg), fy = floorf(yg), fz = floorf(zg);
        float tx = xg - fx, ty = yg - fy, tz = zg - fz;
        unsigned cx = (unsigned)fx, cy = (unsigned)fy, cz = (unsigned)fz;

        unsigned hx0 = cx,      hx1 = cx + 1u;
        unsigned hy0 = cy * P2, hy1 = hy0 + P2;
        unsigned hz0 = cz * P3, hz1 = hz0 + P3;

        const float2* __restrict__ T = (const float2*)tables + (size_t)l * HASH_SIZE;

        unsigned i000 = (hx0 ^ hy0 ^ hz0) & HASH_MASK;
        unsigned i010 = (hx0 ^ hy1 ^ hz0) & HASH_MASK;
        unsigned i001 = (hx0 ^ hy0 ^ hz1) & HASH_MASK;
        unsigned i011 = (hx0 ^ hy1 ^ hz1) & HASH_MASK;

        float2 f000, f100, f010, f110, f001, f101, f011, f111;

        if ((cx & 1u) == 0u) {
            // x0/x1 corners differ by index bit0 -> same aligned 16B block.
            // 4 float4 loads replace 8 float2 loads (half the L2 requests).
            #define PAIR_LOAD(ia, fa, fb)                                   \
                {                                                           \
                    f4 q = *(const f4*)(T + ((ia) & ~1u));                  \
                    float2 lo = {q.x, q.y}, hi = {q.z, q.w};                \
                    bool b = ((ia) & 1u) != 0u;                             \
                    fa = b ? hi : lo;                                       \
                    fb = b ? lo : hi;                                       \
                }
            PAIR_LOAD(i000, f000, f100);
            PAIR_LOAD(i010, f010, f110);
            PAIR_LOAD(i001, f001, f101);
            PAIR_LOAD(i011, f011, f111);
            #undef PAIR_LOAD
        } else {
            unsigned dx = cx ^ (cx + 1u);
            f000 = T[i000];
            f100 = T[i000 ^ dx];
            f010 = T[i010];
            f110 = T[i010 ^ dx];
            f001 = T[i001];
            f101 = T[i001 ^ dx];
            f011 = T[i011];
            f111 = T[i011 ^ dx];
        }

        float wx0 = 1.0f - tx, wx1 = tx;
        float wy0 = 1.0f - ty, wy1 = ty;
        float wz0 = 1.0f - tz, wz1 = tz;

        float w000 = wx0 * wy0 * wz0;
        float w100 = wx1 * wy0 * wz0;
        float w010 = wx0 * wy1 * wz0;
        float w110 = wx1 * wy1 * wz0;
        float w001 = wx0 * wy0 * wz1;
        float w101 = wx1 * wy0 * wz1;
        float w011 = wx0 * wy1 * wz1;
        float w111 = wx1 * wy1 * wz1;

        float a0 = w000 * f000.x;
        float a1 = w000 * f000.y;
        a0 += w100 * f100.x;  a1 += w100 * f100.y;
        a0 += w010 * f010.x;  a1 += w010 * f010.y;
        a0 += w110 * f110.x;  a1 += w110 * f110.y;
        a0 += w001 * f001.x;  a1 += w001 * f001.y;
        a0 += w101 * f101.x;  a1 += w101 * f101.y;
        a0 += w011 * f011.x;  a1 += w011 * f011.y;
        a0 += w111 * f111.x;  a1 += w111 * f111.y;

        o[2 * l + 0] = a0;
        o[2 * l + 1] = a1;
    }

    // nt stores: keep the 128MB output stream out of L2 so tables own it
    // (r2 showed plain stores cost ~+0.2GB FETCH and ~+50us).
    float* op = out + (size_t)i * 32;
    #pragma unroll
    for (int k = 0; k < 8; ++k) {
        f4 v;
        v.x = o[4 * k + 0];
        v.y = o[4 * k + 1];
        v.z = o[4 * k + 2];
        v.w = o[4 * k + 3];
        __builtin_nontemporal_store(v, (f4*)(op + 4 * k));
    }
}

extern "C" void kernel_launch(void* const* d_in, const int* in_sizes, int n_in,
                              void* d_out, int out_size, void* d_ws, size_t ws_size,
                              hipStream_t stream) {
    const float* x = (const float*)d_in[0];
    const float* tables = (const float*)d_in[1];
    float* out = (float*)d_out;
    float* part = (float*)d_ws;                 // 256*6 floats
    float* mm = (float*)d_ws + 2048;            // 6 floats, separate region
    int n = in_sizes[0] / 3;

    // Replicate the reference's host-side resolution computation (libm f64).
    ResArr res;
    double growth = exp((log(512.0) - log(16.0)) / 15.0);
    for (int l = 0; l < 16; ++l) {
        res.r[l] = (float)(int)(16.0 * pow(growth, (double)l));
    }

    he_minmax1<<<256, 256, 0, stream>>>(x, n, part);
    he_minmax2<<<1, 256, 0, stream>>>(part, mm);
    int blocks = (n + 255) / 256;
    he_encode<<<blocks, 256, 0, stream>>>(x, tables, mm, out, n, res);
}